// Round 5
// baseline (703.083 us; speedup 1.0000x reference)
//
#include <hip/hip_runtime.h>
#include <cstdint>
#include <cstddef>

// T=8192 tokens, E=64 experts, D=2048, capacity=2*ceil(T/E)=256
#define T_TOK 8192
#define NE    64
#define ND    2048
#define CAP   256

#define GEMM_B 256   // gemm blocks: 1 wave each, 32 tokens (2 threads/token)
#define FB     3840  // fill blocks (GEMM_B+FB = 4096 = 256 CU x 16 wg slots)

// ---------------- kernel A: zero-LDS gate GEMM (+epilogue) || zero-fill ----
// blocks [0,GEMM_B): 64 threads, 32 tokens; thread = (token, expert-half).
// blocks [GEMM_B,GEMM_B+FB): 64 threads, grid-stride float4 zero of d_out.
// NO __shared__ in this kernel: fill blocks must not reserve LDS.
__global__ __launch_bounds__(64) void kA(
    const float* __restrict__ x, const float* __restrict__ wg,
    const float* __restrict__ gum,
    int* __restrict__ idx1o, int* __restrict__ idx2o,
    float* __restrict__ g1o, float* __restrict__ g2o,
    float* __restrict__ meb,
    float4* __restrict__ o4, long n4, float* __restrict__ o, long n) {
  const int lane = threadIdx.x;     // 0..63

  if (blockIdx.x >= GEMM_B) {
    long i = (long)(blockIdx.x - GEMM_B) * 64 + lane;
    const long stride = (long)FB * 64;
    const float4 z = make_float4(0.f, 0.f, 0.f, 0.f);
    for (; i < n4; i += stride) o4[i] = z;
    if (blockIdx.x == GEMM_B && lane == 0) {
      for (long j = n4 * 4; j < n; ++j) o[j] = 0.f;  // odd tail element
    }
    return;
  }

  const int tr = lane >> 1;         // token within block 0..31
  const int eh = lane & 1;          // expert half: experts [eh*32, eh*32+32)
  const int t  = blockIdx.x * 32 + tr;
  const float* __restrict__ xr = x + (size_t)t * ND;
  const float* __restrict__ wr = wg + (size_t)eh * 32 * ND;

  float acc[32];
#pragma unroll
  for (int j = 0; j < 32; ++j) acc[j] = 0.f;

  // K loop: 16 floats of x per step (one 64B line per thread per step).
  for (int k = 0; k < ND; k += 16) {
    float4 xv[4];
#pragma unroll
    for (int q = 0; q < 4; ++q)
      xv[q] = *reinterpret_cast<const float4*>(xr + k + 4 * q);
#pragma unroll
    for (int g = 0; g < 8; ++g) {
      const float* __restrict__ wb = wr + (size_t)(g * 4) * ND + k;
#pragma unroll
      for (int q = 0; q < 4; ++q) {
        float4 w0 = *reinterpret_cast<const float4*>(wb + 0 * ND + 4 * q);
        float4 w1 = *reinterpret_cast<const float4*>(wb + 1 * ND + 4 * q);
        float4 w2 = *reinterpret_cast<const float4*>(wb + 2 * ND + 4 * q);
        float4 w3 = *reinterpret_cast<const float4*>(wb + 3 * ND + 4 * q);
        const float4 xq = xv[q];
        acc[g*4+0] = fmaf(xq.x, w0.x, fmaf(xq.y, w0.y, fmaf(xq.z, w0.z, fmaf(xq.w, w0.w, acc[g*4+0]))));
        acc[g*4+1] = fmaf(xq.x, w1.x, fmaf(xq.y, w1.y, fmaf(xq.z, w1.z, fmaf(xq.w, w1.w, acc[g*4+1]))));
        acc[g*4+2] = fmaf(xq.x, w2.x, fmaf(xq.y, w2.y, fmaf(xq.z, w2.z, fmaf(xq.w, w2.w, acc[g*4+2]))));
        acc[g*4+3] = fmaf(xq.x, w3.x, fmaf(xq.y, w3.y, fmaf(xq.z, w3.z, fmaf(xq.w, w3.w, acc[g*4+3]))));
      }
    }
  }

  // ---- epilogue, all in registers; pair (lane, lane^1) = one token ----
  // softmax max & sum
  float m = acc[0];
#pragma unroll
  for (int j = 1; j < 32; ++j) m = fmaxf(m, acc[j]);
  m = fmaxf(m, __shfl_xor(m, 1));
  float s = 0.f;
#pragma unroll
  for (int j = 0; j < 32; ++j) s += expf(acc[j] - m);
  s += __shfl_xor(s, 1);

  // argmax1 over logits (first-index tie-break; softmax is monotonic)
  float v1 = acc[0]; int j1 = 0;
#pragma unroll
  for (int j = 1; j < 32; ++j)
    if (acc[j] > v1) { v1 = acc[j]; j1 = j; }
  int i1 = eh * 32 + j1;
  {
    float vp = __shfl_xor(v1, 1); int ip = __shfl_xor(i1, 1);
    const bool mine = eh == 0 ? (v1 >= vp) : (v1 > vp);  // lower index wins ties
    v1 = mine ? v1 : vp; i1 = mine ? i1 : ip;
  }

  // argmax2 over logits+gumbel with i1 masked out
  float gv[32];
  {
    const float4* gp = reinterpret_cast<const float4*>(gum + (size_t)t * NE + eh * 32);
#pragma unroll
    for (int q = 0; q < 8; ++q) {
      float4 g4 = gp[q];
      gv[q*4+0] = g4.x; gv[q*4+1] = g4.y; gv[q*4+2] = g4.z; gv[q*4+3] = g4.w;
    }
  }
  float v2 = -__builtin_inff(); int j2 = 0;
#pragma unroll
  for (int j = 0; j < 32; ++j) {
    float w = (eh * 32 + j == i1) ? -__builtin_inff() : acc[j] + gv[j];
    if (w > v2) { v2 = w; j2 = j; }
  }
  int i2 = eh * 32 + j2;
  {
    float vq = __shfl_xor(v2, 1); int iq = __shfl_xor(i2, 1);
    const bool mine = eh == 0 ? (v2 >= vq) : (v2 > vq);
    i2 = mine ? i2 : iq;
  }

  // convert logits -> gates in-place
#pragma unroll
  for (int j = 0; j < 32; ++j) acc[j] = expf(acc[j] - m) / s;

  float gl1 = ((i1 >> 5) == eh) ? acc[i1 & 31] : 0.f;
  const float g1v = gl1 + __shfl_xor(gl1, 1);
  float gl2 = ((i2 >> 5) == eh) ? acc[i2 & 31] : 0.f;
  const float g2v = gl2 + __shfl_xor(gl2, 1);

  if (eh == 0) {
    idx1o[t] = i1; idx2o[t] = i2; g1o[t] = g1v; g2o[t] = g2v;
  }

  // per-wave me partials: butterfly over same-parity lanes (dist 2..32)
#pragma unroll
  for (int d = 2; d < 64; d <<= 1)
#pragma unroll
    for (int j = 0; j < 32; ++j) acc[j] += __shfl_xor(acc[j], d);

  if (tr == 0) {  // lanes 0 (experts 0..31) and 1 (experts 32..63)
    float* mrow = meb + (size_t)blockIdx.x * NE + eh * 32;
#pragma unroll
    for (int j = 0; j < 32; j += 4) {
      float4 v = make_float4(acc[j], acc[j+1], acc[j+2], acc[j+3]);
      *reinterpret_cast<float4*>(mrow + j) = v;
    }
  }
}

// ------------------------------------------------- per-expert token scan
__global__ __launch_bounds__(256) void k_scan(
    const int* __restrict__ idx1, const int* __restrict__ idx2,
    int* __restrict__ loc1, int* __restrict__ loc2, int* __restrict__ cnt1) {
  const int e = blockIdx.x;
  const int tid = threadIdx.x;
  const int base = tid * 32;
  int c1 = 0, c2 = 0;
  for (int i = 0; i < 32; ++i) {
    c1 += (idx1[base + i] == e);
    c2 += (idx2[base + i] == e);
  }
  const int lane = tid & 63, wave = tid >> 6;
  int s1 = c1, s2 = c2;
#pragma unroll
  for (int o = 1; o < 64; o <<= 1) {
    int t1 = __shfl_up(s1, o), t2 = __shfl_up(s2, o);
    if (lane >= o) { s1 += t1; s2 += t2; }
  }
  __shared__ int wt1[4], wt2[4];
  if (lane == 63) { wt1[wave] = s1; wt2[wave] = s2; }
  __syncthreads();
  int off1 = 0, off2 = 0, tot1 = 0;
#pragma unroll
  for (int w = 0; w < 4; ++w) {
    tot1 += wt1[w];
    if (w < wave) { off1 += wt1[w]; off2 += wt2[w]; }
  }
  int p1 = off1 + s1 - c1;          // exclusive prefix = token rank in expert
  int p2 = off2 + s2 - c2 + tot1;   // + sum(mask1[:,e]) per reference
  for (int i = 0; i < 32; ++i) {
    if (idx1[base + i] == e) loc1[base + i] = p1++;
    if (idx2[base + i] == e) loc2[base + i] = p2++;
  }
  if (tid == 0) cnt1[e] = tot1;
}

// ------------------------------------- scatter combine/dispatch + l_aux
__global__ __launch_bounds__(256) void k_scat(
    const int* __restrict__ idx1, const int* __restrict__ idx2,
    const float* __restrict__ g1, const float* __restrict__ g2,
    const int* __restrict__ loc1, const int* __restrict__ loc2,
    const float* __restrict__ meb, const int* __restrict__ cnt1,
    float* __restrict__ out) {
  if (blockIdx.x == T_TOK / 256) {
    const int lane = threadIdx.x;
    if (lane >= 64) return;
    float ms = 0.f;
    for (int b = 0; b < GEMM_B; ++b) ms += meb[(size_t)b * NE + lane];
    const float me = ms / (float)T_TOK;
    const float ce = (float)cnt1[lane] / (float)T_TOK;
    float v = me * ce;
#pragma unroll
    for (int o = 32; o; o >>= 1) v += __shfl_xor(v, o);
    if (lane == 0) out[0] = v * (float)NE;  // mean(me*ce)*E*E = sum*E
    return;
  }
  const int t = blockIdx.x * 256 + threadIdx.x;
  const int l1 = loc1[t], l2 = loc2[t];
  const bool k1 = l1 < CAP, k2 = l2 < CAP;
  const float a = k1 ? g1[t] : 0.f;
  const float b = k2 ? g2[t] : 0.f;
  const float denom = fmaxf(a + b, 1.1920929e-07f);  // finfo(f32).eps
  float* cw = out + 1;
  float* dm = out + 1 + (size_t)T_TOK * NE * CAP;
  if (k1) {
    size_t o = ((size_t)t * NE + idx1[t]) * CAP + l1;
    cw[o] = a / denom; dm[o] = 1.0f;
  }
  if (k2) {
    size_t o = ((size_t)t * NE + idx2[t]) * CAP + l2;
    cw[o] = b / denom; dm[o] = 1.0f;
  }
}

// ---------------------------------------------------------------- launcher
extern "C" void kernel_launch(void* const* d_in, const int* in_sizes, int n_in,
                              void* d_out, int out_size, void* d_ws, size_t ws_size,
                              hipStream_t stream) {
  const float* x   = (const float*)d_in[0];   // [8192, 2048]
  const float* wg  = (const float*)d_in[1];   // [64, 2048]
  const float* gum = (const float*)d_in[2];   // [8192, 64]
  float* out = (float*)d_out;

  // workspace layout (~261 KB)
  char* ws = (char*)d_ws;
  int*   idx1 = (int*)(ws + 0);
  int*   idx2 = (int*)(ws + 32768);
  float* g1   = (float*)(ws + 65536);
  float* g2   = (float*)(ws + 98304);
  int*   loc1 = (int*)(ws + 131072);
  int*   loc2 = (int*)(ws + 163840);
  int*   cnt1 = (int*)(ws + 196608);
  float* meb  = (float*)(ws + 197120);        // [256][64]

  const long n  = (long)out_size;             // 268,435,457 floats
  const long n4 = n >> 2;

  kA<<<dim3(GEMM_B + FB), dim3(64), 0, stream>>>(
      x, wg, gum, idx1, idx2, g1, g2, meb, (float4*)out, n4, out, n);
  k_scan<<<dim3(NE), dim3(256), 0, stream>>>(idx1, idx2, loc1, loc2, cnt1);
  k_scat<<<dim3(T_TOK / 256 + 1), dim3(256), 0, stream>>>(
      idx1, idx2, g1, g2, loc1, loc2, meb, cnt1, out);
}

// Round 6
// 293.386 us; speedup vs baseline: 2.3964x; 2.3964x over previous
//
#include <hip/hip_runtime.h>
#include <cstdint>
#include <cstddef>

// T=8192 tokens, E=64 experts, D=2048, capacity=2*ceil(T/E)=256
#define T_TOK 8192
#define NE    64
#define ND    2048
#define CAP   256

#define GB2 256    // gemm blocks: 128 token-tiles x 2 K-halves
#define FB2 3840   // fill blocks
#define MEB_B 128  // meb rows (k_epi blocks)

// ---------------- kernel F: split-K gate GEMM (partials) || zero-fill ----
// blocks [0,GB2): 64tok x 64exp x K/2 fp32 GEMM -> lp partials
// blocks [GB2,GB2+FB2): grid-stride float4 zero of d_out
// LDS = 34.8 KB -> 4 blocks/CU, so fill branches keep >=16 waves/CU.
__global__ __launch_bounds__(256) void kF(
    const float* __restrict__ x, const float* __restrict__ wg,
    float* __restrict__ lp,
    float4* __restrict__ o4, long n4, float* __restrict__ o, long n) {
  __shared__ float xs[64][68];   // x tile [token][k], row stride 68
  __shared__ float wk[64][68];   // wg tile TRANSPOSED [k][expert]

  const int tid = threadIdx.x;

  if (blockIdx.x >= GB2) {
    long i = (long)(blockIdx.x - GB2) * 256 + tid;
    const long stride = (long)FB2 * 256;
    const float4 z = make_float4(0.f, 0.f, 0.f, 0.f);
    for (; i < n4; i += stride) o4[i] = z;
    if (blockIdx.x == GB2 && tid == 0) {
      for (long j = n4 * 4; j < n; ++j) o[j] = 0.f;  // odd tail element
    }
    return;
  }

  const int tb = blockIdx.x >> 1;   // token tile 0..127
  const int kb = blockIdx.x & 1;    // K half
  const int t0 = tb * 64;
  const int k0 = kb * (ND / 2);
  const int ty = tid >> 4;          // token group (4 tokens)
  const int tx = tid & 15;          // expert group (4 experts)

  float acc[4][4];
#pragma unroll
  for (int i = 0; i < 4; ++i)
#pragma unroll
    for (int j = 0; j < 4; ++j) acc[i][j] = 0.f;

  for (int kt = k0; kt < k0 + ND / 2; kt += 64) {
    // stage: x [row][k] via b128; wg transposed [k][expert] scalar
#pragma unroll
    for (int i = 0; i < 4; ++i) {
      const int s = tid + i * 256;
      const int r = s >> 4;            // row 0..63
      const int c4 = (s & 15) << 2;    // k offset
      *reinterpret_cast<float4*>(&xs[r][c4]) =
          *reinterpret_cast<const float4*>(x + (size_t)(t0 + r) * ND + kt + c4);
      float4 vw = *reinterpret_cast<const float4*>(wg + (size_t)r * ND + kt + c4);
      wk[c4 + 0][r] = vw.x; wk[c4 + 1][r] = vw.y;
      wk[c4 + 2][r] = vw.z; wk[c4 + 3][r] = vw.w;
    }
    __syncthreads();
#pragma unroll 2
    for (int k4 = 0; k4 < 64; k4 += 4) {
      float4 xa[4];
#pragma unroll
      for (int i = 0; i < 4; ++i)
        xa[i] = *reinterpret_cast<const float4*>(&xs[ty * 4 + i][k4]);
#pragma unroll
      for (int kk = 0; kk < 4; ++kk) {
        float4 wb = *reinterpret_cast<const float4*>(&wk[k4 + kk][tx * 4]);
        const float bw[4] = {wb.x, wb.y, wb.z, wb.w};
#pragma unroll
        for (int i = 0; i < 4; ++i) {
          const float* ax = reinterpret_cast<const float*>(&xa[i]);
          const float a = ax[kk];
#pragma unroll
          for (int j = 0; j < 4; ++j) acc[i][j] = fmaf(a, bw[j], acc[i][j]);
        }
      }
    }
    __syncthreads();
  }

  // write partial logits [kb][token][expert]
  float* dst = lp + (size_t)kb * T_TOK * NE;
#pragma unroll
  for (int i = 0; i < 4; ++i) {
    float4 v = make_float4(acc[i][0], acc[i][1], acc[i][2], acc[i][3]);
    *reinterpret_cast<float4*>(dst + (size_t)(t0 + ty * 4 + i) * NE + tx * 4) = v;
  }
}

// ------------------------------------------------- epilogue: softmax/argmax
// 128 blocks x 256 threads; one wave = 16 tokens; lane = expert.
__global__ __launch_bounds__(256) void k_epi(
    const float* __restrict__ lp, const float* __restrict__ gum,
    int* __restrict__ idx1o, int* __restrict__ idx2o,
    float* __restrict__ g1o, float* __restrict__ g2o,
    float* __restrict__ meb) {
  __shared__ float mred[4][NE];
  const int tid = threadIdx.x;
  const int wave = tid >> 6;
  const int lane = tid & 63;
  const int t0 = blockIdx.x * 64;
  float meacc = 0.f;
  for (int tt = wave * 16; tt < wave * 16 + 16; ++tt) {
    const int t = t0 + tt;
    const float logit = lp[(size_t)t * NE + lane] +
                        lp[(size_t)(T_TOK + t) * NE + lane];
    // softmax across the wave (lane = expert)
    float m = logit;
#pragma unroll
    for (int o = 32; o; o >>= 1) m = fmaxf(m, __shfl_xor(m, o));
    const float ex = expf(logit - m);
    float s = ex;
#pragma unroll
    for (int o = 32; o; o >>= 1) s += __shfl_xor(s, o);
    const float gate = ex / s;
    meacc += gate;
    // argmax over logits (first-index tie-break)
    float v1 = logit; int i1 = lane;
#pragma unroll
    for (int o = 32; o; o >>= 1) {
      float vv = __shfl_xor(v1, o); int jj = __shfl_xor(i1, o);
      if (vv > v1 || (vv == v1 && jj < i1)) { v1 = vv; i1 = jj; }
    }
    // second expert: gumbel-noised logits, top-1 masked
    float v2 = (lane == i1) ? -__builtin_inff() : logit + gum[(size_t)t * NE + lane];
    int i2 = lane;
#pragma unroll
    for (int o = 32; o; o >>= 1) {
      float vv = __shfl_xor(v2, o); int jj = __shfl_xor(i2, o);
      if (vv > v2 || (vv == v2 && jj < i2)) { v2 = vv; i2 = jj; }
    }
    const float gv1 = __shfl(gate, i1);
    const float gv2 = __shfl(gate, i2);
    if (lane == 0) {
      idx1o[t] = i1; idx2o[t] = i2; g1o[t] = gv1; g2o[t] = gv2;
    }
  }
  mred[wave][lane] = meacc;
  __syncthreads();
  if (wave == 0) {
    float sm = mred[0][lane] + mred[1][lane] + mred[2][lane] + mred[3][lane];
    meb[(size_t)blockIdx.x * NE + lane] = sm;
  }
}

// ------------------------------------------------- per-expert token scan
__global__ __launch_bounds__(256) void k_scan(
    const int* __restrict__ idx1, const int* __restrict__ idx2,
    int* __restrict__ loc1, int* __restrict__ loc2, int* __restrict__ cnt1) {
  const int e = blockIdx.x;
  const int tid = threadIdx.x;
  const int base = tid * 32;
  int c1 = 0, c2 = 0;
  for (int i = 0; i < 32; ++i) {
    c1 += (idx1[base + i] == e);
    c2 += (idx2[base + i] == e);
  }
  const int lane = tid & 63, wave = tid >> 6;
  int s1 = c1, s2 = c2;
#pragma unroll
  for (int o = 1; o < 64; o <<= 1) {
    int t1 = __shfl_up(s1, o), t2 = __shfl_up(s2, o);
    if (lane >= o) { s1 += t1; s2 += t2; }
  }
  __shared__ int wt1[4], wt2[4];
  if (lane == 63) { wt1[wave] = s1; wt2[wave] = s2; }
  __syncthreads();
  int off1 = 0, off2 = 0, tot1 = 0;
#pragma unroll
  for (int w = 0; w < 4; ++w) {
    tot1 += wt1[w];
    if (w < wave) { off1 += wt1[w]; off2 += wt2[w]; }
  }
  int p1 = off1 + s1 - c1;          // exclusive prefix = token rank in expert
  int p2 = off2 + s2 - c2 + tot1;   // + sum(mask1[:,e]) per reference
  for (int i = 0; i < 32; ++i) {
    if (idx1[base + i] == e) loc1[base + i] = p1++;
    if (idx2[base + i] == e) loc2[base + i] = p2++;
  }
  if (tid == 0) cnt1[e] = tot1;
}

// ------------------------------------- scatter combine/dispatch + l_aux
__global__ __launch_bounds__(256) void k_scat(
    const int* __restrict__ idx1, const int* __restrict__ idx2,
    const float* __restrict__ g1, const float* __restrict__ g2,
    const int* __restrict__ loc1, const int* __restrict__ loc2,
    const float* __restrict__ meb, const int* __restrict__ cnt1,
    float* __restrict__ out) {
  if (blockIdx.x == T_TOK / 256) {
    const int lane = threadIdx.x;
    if (lane >= 64) return;
    float ms = 0.f;
    for (int b = 0; b < MEB_B; ++b) ms += meb[(size_t)b * NE + lane];
    const float me = ms / (float)T_TOK;
    const float ce = (float)cnt1[lane] / (float)T_TOK;
    float v = me * ce;
#pragma unroll
    for (int o = 32; o; o >>= 1) v += __shfl_xor(v, o);
    if (lane == 0) out[0] = v * (float)NE;  // mean(me*ce)*E*E = sum*E
    return;
  }
  const int t = blockIdx.x * 256 + threadIdx.x;
  const int l1 = loc1[t], l2 = loc2[t];
  const bool k1 = l1 < CAP, k2 = l2 < CAP;
  const float a = k1 ? g1[t] : 0.f;
  const float b = k2 ? g2[t] : 0.f;
  const float denom = fmaxf(a + b, 1.1920929e-07f);  // finfo(f32).eps
  float* cw = out + 1;
  float* dm = out + 1 + (size_t)T_TOK * NE * CAP;
  if (k1) {
    size_t o = ((size_t)t * NE + idx1[t]) * CAP + l1;
    cw[o] = a / denom; dm[o] = 1.0f;
  }
  if (k2) {
    size_t o = ((size_t)t * NE + idx2[t]) * CAP + l2;
    cw[o] = b / denom; dm[o] = 1.0f;
  }
}

// ---------------------------------------------------------------- launcher
extern "C" void kernel_launch(void* const* d_in, const int* in_sizes, int n_in,
                              void* d_out, int out_size, void* d_ws, size_t ws_size,
                              hipStream_t stream) {
  const float* x   = (const float*)d_in[0];   // [8192, 2048]
  const float* wg  = (const float*)d_in[1];   // [64, 2048]
  const float* gum = (const float*)d_in[2];   // [8192, 64]
  float* out = (float*)d_out;

  // workspace layout (~4.5 MB)
  char* ws = (char*)d_ws;
  float* lp   = (float*)(ws + 0);             // [2][8192][64] = 4 MB
  int*   idx1 = (int*)(ws + 4194304);
  int*   idx2 = (int*)(ws + 4227072);
  float* g1   = (float*)(ws + 4259840);
  float* g2   = (float*)(ws + 4292608);
  int*   loc1 = (int*)(ws + 4325376);
  int*   loc2 = (int*)(ws + 4358144);
  int*   cnt1 = (int*)(ws + 4390912);
  float* meb  = (float*)(ws + 4391168);       // [128][64]

  const long n  = (long)out_size;             // 268,435,457 floats
  const long n4 = n >> 2;

  kF<<<dim3(GB2 + FB2), dim3(256), 0, stream>>>(x, wg, lp, (float4*)out, n4, out, n);
  k_epi<<<dim3(T_TOK / 64), dim3(256), 0, stream>>>(lp, gum, idx1, idx2, g1, g2, meb);
  k_scan<<<dim3(NE), dim3(256), 0, stream>>>(idx1, idx2, loc1, loc2, cnt1);
  k_scat<<<dim3(T_TOK / 256 + 1), dim3(256), 0, stream>>>(
      idx1, idx2, g1, g2, loc1, loc2, meb, cnt1, out);
}